// Round 1
// baseline (1445.595 us; speedup 1.0000x reference)
//
#include <hip/hip_runtime.h>
#include <hip/hip_fp16.h>
#include <cstdint>
#include <cstddef>

#define B_  32
#define N_  512
#define T_  24
#define F_  64
#define FA_ 74
#define NC  1536   // T_*F_ columns per node-row

typedef __attribute__((ext_vector_type(8))) _Float16 half8;
typedef __attribute__((ext_vector_type(4))) float floatx4;

// ws float layout:
//  [0,74)               rsW (rowsum of W)
//  [128,704)            W2 (symmetric, row-major 24x24)
//  [1536,132608)        adjH f16[512*512]  = 0.125*sig(alpha_i)*adj[i][k]
//  [132608,12715520)    xT  f16[b][c][k]   (32*1536*512)
//  [12715520,13108736)  S   fp32[b][t][k]  (rowsum over f of x)
#define WS_ADJ 1536
#define WS_XT  132608
#define WS_S   12715520

#define AS1(p) ((const __attribute__((address_space(1))) void*)(p))
#define AS3(p) ((__attribute__((address_space(3))) void*)(p))

union h2u { _Float16 h; unsigned short u; };
union pk2 { unsigned int u; _Float16 h[2]; };

__global__ __launch_bounds__(256) void params_kernel(
    const float* __restrict__ w, const float* __restrict__ d,
    const float* __restrict__ w2, const float* __restrict__ d2,
    float* __restrict__ ws) {
  __shared__ float cs[FA_];
  int tid = threadIdx.x;
  if (tid < FA_) {
    float s = 0.f;
    for (int n = 0; n < FA_; ++n) s += w[n * FA_ + tid];
    cs[tid] = s;
  }
  __syncthreads();
  if (tid < FA_) {
    float s = 0.f;
    for (int p = 0; p < FA_; ++p) {
      float dc = fminf(fmaxf(d[p], 0.f), 1.f);
      s += w[tid * FA_ + p] * dc * cs[p];
    }
    ws[tid] = s;
  }
  for (int e = tid; e < T_ * T_; e += 256) {
    int a = e / T_, b = e % T_;
    float s = 0.f;
    for (int p = 0; p < T_; ++p) {
      float dc = fminf(fmaxf(d2[p], 0.f), 1.f);
      s += w2[a * T_ + p] * dc * w2[b * T_ + p];
    }
    ws[128 + e] = s;
  }
}

// adj fp32 -> f16, scaled by 0.125*sigmoid(alpha_i). grid 256x256, 4 elems/thread.
__global__ __launch_bounds__(256) void convert_adj_kernel(
    const float* __restrict__ adj, const float* __restrict__ alpha,
    float* __restrict__ ws) {
  _Float16* adjH = (_Float16*)(ws + WS_ADJ);
  int g = (blockIdx.x * 256 + threadIdx.x) * 4;
  int row = g >> 9;
  float sc = 0.125f / (1.f + __expf(-alpha[row]));
  float4 v = *(const float4*)&adj[g];
  ushort4 u4; h2u cv;
  cv.h = (_Float16)(sc * v.x); u4.x = cv.u;
  cv.h = (_Float16)(sc * v.y); u4.y = cv.u;
  cv.h = (_Float16)(sc * v.z); u4.z = cv.u;
  cv.h = (_Float16)(sc * v.w); u4.w = cv.u;
  *(ushort4*)&adjH[g] = u4;
}

// x[b][k][c] fp32 -> xT[b][c][k] f16, plus S[b][t][k] = sum_f x (fp32).
// 64x64 tiles; each c-tile is exactly one t. grid (24, 8, 32).
__global__ __launch_bounds__(256) void transpose_x_kernel(
    const float* __restrict__ x, float* __restrict__ ws) {
  _Float16* xT = (_Float16*)(ws + WS_XT);
  float* Sp = ws + WS_S;
  __shared__ float tile[64 * 65];
  int tid = threadIdx.x;
  int b = blockIdx.z;
  int t = blockIdx.x;
  int c0 = t * 64;
  int k0 = blockIdx.y * 64;
#pragma unroll
  for (int it = 0; it < 4; ++it) {
    int g = it * 256 + tid;
    int k = g >> 4, c4 = g & 15;
    float4 v = *(const float4*)&x[((size_t)(b * N_ + k0 + k)) * NC + c0 + c4 * 4];
    tile[k * 65 + c4 * 4 + 0] = v.x;
    tile[k * 65 + c4 * 4 + 1] = v.y;
    tile[k * 65 + c4 * 4 + 2] = v.z;
    tile[k * 65 + c4 * 4 + 3] = v.w;
  }
  __syncthreads();
  {
    // S: thread-quad (k, q) sums 16 f each, reduce over q via shfl
    int k = tid >> 2, q = tid & 3;
    float s = 0.f;
#pragma unroll
    for (int j = 0; j < 16; ++j) s += tile[k * 65 + q * 16 + j];
    s += __shfl_xor(s, 1, 64);
    s += __shfl_xor(s, 2, 64);
    if (q == 0) Sp[((size_t)b * T_ + t) * N_ + k0 + k] = s;
  }
#pragma unroll
  for (int it = 0; it < 4; ++it) {
    int hh = it * 256 + tid;
    int c = hh >> 4, k4 = hh & 15;
    ushort4 u4; h2u cv;
    cv.h = (_Float16)tile[(k4 * 4 + 0) * 65 + c]; u4.x = cv.u;
    cv.h = (_Float16)tile[(k4 * 4 + 1) * 65 + c]; u4.y = cv.u;
    cv.h = (_Float16)tile[(k4 * 4 + 2) * 65 + c]; u4.z = cv.u;
    cv.h = (_Float16)tile[(k4 * 4 + 3) * 65 + c]; u4.w = cv.u;
    *(ushort4*)&xT[((size_t)b * NC + c0 + c) * 512 + k0 + k4 * 4] = u4;
  }
}

// Fully fused: acc = (0.125*sig(a)*adj) @ x  via f16 MFMA (128x128 tile, K=512);
// epilogue computes out = relu(acc + 0.5*x + 0.25*tmix + 0.25*S*rsW[f]) write-once,
// plus aug channels f>=64. grid (12, 4, 32), 256 thr.
__global__ __launch_bounds__(256) void gemm_kernel(
    const float* __restrict__ ws, float* __restrict__ out) {
  const _Float16* adjH = (const _Float16*)(ws + WS_ADJ);
  const _Float16* xT = (const _Float16*)(ws + WS_XT);
  const unsigned short* xTu = (const unsigned short*)xT;
  const float* Sp = ws + WS_S;

  // smem map (time-shared):
  //  [0, 33792)      accS 64x132 fp32   (main loop aliases As[0,8192) Bs[8192,16384))
  //  [33792, 50176)  tmU  64x64 uint (2xf16, XOR-swizzled)
  //  [50176, 50368)  coefs[48]
  __shared__ __align__(16) char smem[50368];
  _Float16* As = (_Float16*)smem;
  _Float16* Bs = (_Float16*)(smem + 8192);
  float* accS = (float*)smem;
  unsigned int* tmU = (unsigned int*)(smem + 33792);
  float* coefs = (float*)(smem + 50176);

  int tid = threadIdx.x;
  int b = blockIdx.z;
  int i0 = blockIdx.y * 128;
  int c0 = blockIdx.x * 128;
  int t0 = blockIdx.x * 2;
  int wave = tid >> 6, lane = tid & 63;
  int mw = (wave & 1) * 64, nw = (wave >> 1) * 64;
  int l15 = lane & 15, l4 = lane >> 4;

  // tmix coefficients: 0.25*W2[t0+tl][tp] + 0.5 at tp==t (folds the 0.5*x term)
  if (tid < 48) {
    int tl = tid / 24, tp = tid % 24;
    float cf = 0.25f * ws[128 + (t0 + tl) * 24 + tp];
    if (tp == t0 + tl) cf += 0.5f;
    coefs[tid] = cf;
  }

  floatx4 acc[4][4];
#pragma unroll
  for (int mt = 0; mt < 4; ++mt)
#pragma unroll
    for (int nt = 0; nt < 4; ++nt) acc[mt][nt] = (floatx4){0.f, 0.f, 0.f, 0.f};

  const size_t bC = (size_t)b * NC;
  for (int k0 = 0; k0 < 512; k0 += 32) {
#pragma unroll
    for (int rep = 0; rep < 2; ++rep) {
      int chunk = rep * 256 + tid;
      int r = chunk >> 2;
      int k8 = (chunk & 3) * 8;
      __builtin_amdgcn_global_load_lds(AS1(adjH + (size_t)(i0 + r) * 512 + k0 + k8),
                                       AS3(&As[chunk * 8]), 16, 0, 0);
      __builtin_amdgcn_global_load_lds(AS1(xT + (bC + c0 + r) * 512 + k0 + k8),
                                       AS3(&Bs[chunk * 8]), 16, 0, 0);
    }
    __syncthreads();
    half8 af[4], bfv[4];
#pragma unroll
    for (int mt = 0; mt < 4; ++mt)
      af[mt] = *(const half8*)&As[(mw + mt * 16 + l15) * 32 + l4 * 8];
#pragma unroll
    for (int nt = 0; nt < 4; ++nt)
      bfv[nt] = *(const half8*)&Bs[(nw + nt * 16 + l15) * 32 + l4 * 8];
#pragma unroll
    for (int mt = 0; mt < 4; ++mt)
#pragma unroll
      for (int nt = 0; nt < 4; ++nt)
        acc[mt][nt] = __builtin_amdgcn_mfma_f32_16x16x32_f16(af[mt], bfv[nt], acc[mt][nt], 0, 0, 0);
    __syncthreads();
  }

  // Epilogue: two 64-row halves. h=0 -> waves 0,2 (mw=0); h=1 -> waves 1,3.
  for (int h = 0; h < 2; ++h) {
    if ((wave & 1) == h) {
#pragma unroll
      for (int mt = 0; mt < 4; ++mt)
#pragma unroll
        for (int nt = 0; nt < 4; ++nt)
#pragma unroll
          for (int r = 0; r < 4; ++r)
            accS[(mt * 16 + l4 * 4 + r) * 132 + nw + nt * 16 + l15] = acc[mt][nt][r];
    }
    __syncthreads();

    {
      // row-major phase: lanes vary row -> 128B-coalesced xT (L2-hot) reads
      int row = tid & 63;
      int fj = tid >> 6;
      const unsigned short* xrow = xTu + bC * 512 + (i0 + h * 64 + row);
#pragma unroll
      for (int jj = 0; jj < 16; ++jj) {
        int f = fj * 16 + jj;
        float xv[24];
#pragma unroll
        for (int tp = 0; tp < 24; ++tp) {
          h2u cv; cv.u = xrow[(tp * 64 + f) * 512];
          xv[tp] = (float)cv.h;
        }
        float t0v = 0.f, t1v = 0.f;
#pragma unroll
        for (int tp = 0; tp < 24; ++tp) {
          t0v += coefs[tp] * xv[tp];
          t1v += coefs[24 + tp] * xv[tp];
        }
        pk2 p; p.h[0] = (_Float16)t0v; p.h[1] = (_Float16)t1v;
        tmU[row * 64 + (f ^ (row & 31))] = p.u;   // XOR swizzle: 2-way banks both sides
      }
    }
    __syncthreads();

    {
      // f-major phase: lanes vary f -> 256B-coalesced write-once stores
      int f = tid & 63;
      int rj = tid >> 6;
      float rsWf = ws[f];
#pragma unroll
      for (int jj = 0; jj < 16; ++jj) {
        int row = rj + 4 * jj;
        int grow = i0 + h * 64 + row;
        pk2 p; p.u = tmU[row * 64 + (f ^ (row & 31))];
        float Sv0 = Sp[((size_t)b * T_ + t0) * N_ + grow];
        float Sv1 = Sp[((size_t)b * T_ + t0 + 1) * N_ + grow];
        float v0 = accS[row * 132 + f]      + (float)p.h[0] + 0.25f * Sv0 * rsWf;
        float v1 = accS[row * 132 + 64 + f] + (float)p.h[1] + 0.25f * Sv1 * rsWf;
        size_t o = (((size_t)(b * N_ + grow)) * T_ + t0) * FA_ + f;
        out[o] = fmaxf(v0, 0.f);
        out[o + FA_] = fmaxf(v1, 0.f);
      }
      // aug channels m in [64,74): relu(0.25*S*rsW[m]); 64 rows * 2 t * 10 m = 1280
#pragma unroll
      for (int q = 0; q < 5; ++q) {
        int e = tid + 256 * q;
        int row = e / 20;
        int r20 = e - row * 20;
        int tl = r20 / 10;
        int m = r20 - tl * 10;
        int grow = i0 + h * 64 + row;
        float Sv = Sp[((size_t)b * T_ + t0 + tl) * N_ + grow];
        float val = 0.25f * Sv * ws[64 + m];
        size_t o = (((size_t)(b * N_ + grow)) * T_ + t0 + tl) * FA_ + 64 + m;
        out[o] = fmaxf(val, 0.f);
      }
    }
    __syncthreads();
  }
}

extern "C" void kernel_launch(void* const* d_in, const int* in_sizes, int n_in,
                              void* d_out, int out_size, void* d_ws, size_t ws_size,
                              hipStream_t stream) {
  const float* x     = (const float*)d_in[0];
  const float* adj   = (const float*)d_in[1];
  const float* alpha = (const float*)d_in[2];
  const float* w     = (const float*)d_in[3];
  const float* d     = (const float*)d_in[4];
  const float* w2    = (const float*)d_in[5];
  const float* d2    = (const float*)d_in[6];
  float* out = (float*)d_out;
  float* ws  = (float*)d_ws;

  hipLaunchKernelGGL(params_kernel, dim3(1), dim3(256), 0, stream, w, d, w2, d2, ws);
  hipLaunchKernelGGL(convert_adj_kernel, dim3(256), dim3(256), 0, stream, adj, alpha, ws);
  hipLaunchKernelGGL(transpose_x_kernel, dim3(24, 8, B_), dim3(256), 0, stream, x, ws);
  hipLaunchKernelGGL(gemm_kernel, dim3(12, 4, B_), dim3(256), 0, stream, ws, out);
}

// Round 2
// 353.574 us; speedup vs baseline: 4.0885x; 4.0885x over previous
//
#include <hip/hip_runtime.h>
#include <hip/hip_fp16.h>
#include <cstdint>
#include <cstddef>

#define B_  32
#define N_  512
#define T_  24
#define F_  64
#define FA_ 74
#define NC  1536   // T_*F_ columns per node-row

typedef __attribute__((ext_vector_type(8))) _Float16 half8;
typedef __attribute__((ext_vector_type(4))) float floatx4;

// ws float layout:
//  [0,74)               rsW (rowsum of W)
//  [128,704)            W2 (symmetric, row-major 24x24)
//  [1536,132608)        adjH f16[512*512]  = 0.125*sig(alpha_i)*adj[i][k]
//  [132608,12715520)    xT  f16[b][c][k]   (32*1536*512)  ~48 MB
//  [12715520,25298432)  E0  f16[b][k][c]   (32*512*1536)  ~48 MB
#define WS_ADJ 1536
#define WS_XT  132608
#define WS_E0  12715520

#define AS1(p) ((const __attribute__((address_space(1))) void*)(p))
#define AS3(p) ((__attribute__((address_space(3))) void*)(p))

union h2u { _Float16 h; unsigned short u; };

__global__ __launch_bounds__(256) void params_kernel(
    const float* __restrict__ w, const float* __restrict__ d,
    const float* __restrict__ w2, const float* __restrict__ d2,
    float* __restrict__ ws) {
  __shared__ float cs[FA_];
  int tid = threadIdx.x;
  if (tid < FA_) {
    float s = 0.f;
    for (int n = 0; n < FA_; ++n) s += w[n * FA_ + tid];
    cs[tid] = s;
  }
  __syncthreads();
  if (tid < FA_) {
    float s = 0.f;
    for (int p = 0; p < FA_; ++p) {
      float dc = fminf(fmaxf(d[p], 0.f), 1.f);
      s += w[tid * FA_ + p] * dc * cs[p];
    }
    ws[tid] = s;
  }
  for (int e = tid; e < T_ * T_; e += 256) {
    int a = e / T_, b = e % T_;
    float s = 0.f;
    for (int p = 0; p < T_; ++p) {
      float dc = fminf(fmaxf(d2[p], 0.f), 1.f);
      s += w2[a * T_ + p] * dc * w2[b * T_ + p];
    }
    ws[128 + e] = s;
  }
}

// adj fp32 -> f16, scaled by 0.125*sigmoid(alpha_i). grid 256x256, 4 elems/thread.
__global__ __launch_bounds__(256) void convert_adj_kernel(
    const float* __restrict__ adj, const float* __restrict__ alpha,
    float* __restrict__ ws) {
  _Float16* adjH = (_Float16*)(ws + WS_ADJ);
  int g = (blockIdx.x * 256 + threadIdx.x) * 4;
  int row = g >> 9;
  float sc = 0.125f / (1.f + __expf(-alpha[row]));
  float4 v = *(const float4*)&adj[g];
  ushort4 u4; h2u cv;
  cv.h = (_Float16)(sc * v.x); u4.x = cv.u;
  cv.h = (_Float16)(sc * v.y); u4.y = cv.u;
  cv.h = (_Float16)(sc * v.z); u4.z = cv.u;
  cv.h = (_Float16)(sc * v.w); u4.w = cv.u;
  *(ushort4*)&adjH[g] = u4;
}

// x[b][k][c] fp32 -> xT[b][c][k] f16. 64x64 tiles. grid (24, 8, 32).
__global__ __launch_bounds__(256) void transpose_x_kernel(
    const float* __restrict__ x, float* __restrict__ ws) {
  _Float16* xT = (_Float16*)(ws + WS_XT);
  __shared__ float tile[64 * 65];
  int tid = threadIdx.x;
  int b = blockIdx.z;
  int c0 = blockIdx.x * 64;
  int k0 = blockIdx.y * 64;
#pragma unroll
  for (int it = 0; it < 4; ++it) {
    int g = it * 256 + tid;
    int k = g >> 4, c4 = g & 15;
    float4 v = *(const float4*)&x[((size_t)(b * N_ + k0 + k)) * NC + c0 + c4 * 4];
    tile[k * 65 + c4 * 4 + 0] = v.x;
    tile[k * 65 + c4 * 4 + 1] = v.y;
    tile[k * 65 + c4 * 4 + 2] = v.z;
    tile[k * 65 + c4 * 4 + 3] = v.w;
  }
  __syncthreads();
#pragma unroll
  for (int it = 0; it < 4; ++it) {
    int hh = it * 256 + tid;
    int c = hh >> 4, k4 = hh & 15;
    ushort4 u4; h2u cv;
    cv.h = (_Float16)tile[(k4 * 4 + 0) * 65 + c]; u4.x = cv.u;
    cv.h = (_Float16)tile[(k4 * 4 + 1) * 65 + c]; u4.y = cv.u;
    cv.h = (_Float16)tile[(k4 * 4 + 2) * 65 + c]; u4.z = cv.u;
    cv.h = (_Float16)tile[(k4 * 4 + 3) * 65 + c]; u4.w = cv.u;
    *(ushort4*)&xT[((size_t)b * NC + c0 + c) * 512 + k0 + k4 * 4] = u4;
  }
}

// E0[b][k][c] = 0.5*x + 0.25*tmix + 0.25*S*rsW[f]  (f16, natural layout);
// also writes aug channels f>=64 of out: relu(0.25*S*rsW[m]).
// grid 32*128 (4 nodes/block), 256 thr, thread <-> (node, f).
__global__ __launch_bounds__(256) void e_kernel(
    const float* __restrict__ x, float* __restrict__ ws, float* __restrict__ out) {
  __shared__ float xs[4 * NC];            // 24576 B
  __shared__ unsigned short es[4 * NC];   // 12288 B
  __shared__ float Ss[4 * T_];
  int tid = threadIdx.x;
  int blk = blockIdx.x;
  int b = blk >> 7;
  int i0 = (blk & 127) << 2;
  const float* xb = x + (size_t)(b * N_ + i0) * NC;
#pragma unroll
  for (int it = 0; it < 6; ++it) {
    int g = it * 256 + tid;
    *(float4*)&xs[g * 4] = *(const float4*)&xb[g * 4];
  }
  __syncthreads();

  int node = tid >> 6, f = tid & 63;
  float xcol[24];
#pragma unroll
  for (int t = 0; t < 24; ++t) xcol[t] = xs[node * NC + t * 64 + f];

  // S[t] = wave-wide sum over f (lanes of this wave are exactly f 0..63)
  float S[24];
#pragma unroll
  for (int t = 0; t < 24; ++t) S[t] = xcol[t];
#pragma unroll
  for (int off = 32; off >= 1; off >>= 1) {
#pragma unroll
    for (int t = 0; t < 24; ++t) S[t] += __shfl_xor(S[t], off, 64);
  }
  if ((tid & 63) == 0) {
#pragma unroll
    for (int t = 0; t < 24; ++t) Ss[node * 24 + t] = S[t];
  }

  const float* __restrict__ W2p = ws + 128;   // uniform scalar loads
  float rsWf = ws[f];
#pragma unroll
  for (int t = 0; t < 24; ++t) {
    float a = 0.f;
#pragma unroll
    for (int tp = 0; tp < 24; ++tp) a += xcol[tp] * W2p[t * 24 + tp];
    float val = 0.5f * xcol[t] + 0.25f * S[t] * rsWf + 0.25f * a;
    h2u cv; cv.h = (_Float16)val;
    es[node * NC + t * 64 + f] = cv.u;
  }
  __syncthreads();

  // flush E0 tile: 4*1536 f16 = 12288 B = 768 float4, coalesced
  _Float16* E0 = (_Float16*)(ws + WS_E0);
  float4* dst = (float4*)(E0 + (size_t)(b * N_ + i0) * NC);
#pragma unroll
  for (int it = 0; it < 3; ++it) {
    int g = it * 256 + tid;
    dst[g] = *(float4*)&es[g * 8];
  }

  // aug channels: 4 nodes * 24 t * 10 m = 960
#pragma unroll
  for (int it = 0; it < 4; ++it) {
    int e2 = it * 256 + tid;
    if (e2 < 960) {
      int nd = e2 / 240;
      int rem = e2 - nd * 240;
      int t = rem / 10;
      int m = rem - t * 10;
      float val = 0.25f * Ss[nd * 24 + t] * ws[64 + m];
      size_t o = ((size_t)(b * N_ + i0 + nd) * T_ + t) * FA_ + 64 + m;
      out[o] = fmaxf(val, 0.f);
    }
  }
}

// MFMA GEMM: acc = (0.125*sig(a)*adj) @ x ; out = relu(acc + E0) write-once.
// 128x128 tile, K=512, BK=64 (XOR-swizzled LDS), grid (12, 4, 32), 256 thr.
__global__ __launch_bounds__(256) void gemm_kernel(
    const float* __restrict__ ws, float* __restrict__ out) {
  const _Float16* adjH = (const _Float16*)(ws + WS_ADJ);
  const _Float16* xT   = (const _Float16*)(ws + WS_XT);
  const _Float16* E0   = (const _Float16*)(ws + WS_E0);

  // smem map: main loop As[0,16384) Bs[16384,32768);
  // epilogue accS fp32 64x132 [0,33792) ; Es f16 64x128 [33792,50176)
  __shared__ __align__(16) char smem[50176];
  _Float16* As = (_Float16*)smem;
  _Float16* Bs = (_Float16*)(smem + 16384);
  float* accS = (float*)smem;
  _Float16* Es = (_Float16*)(smem + 33792);

  int tid = threadIdx.x;
  int b = blockIdx.z;
  int i0 = blockIdx.y * 128;
  int c0 = blockIdx.x * 128;
  int t0 = blockIdx.x * 2;
  int wave = tid >> 6, lane = tid & 63;
  int mw = (wave & 1) * 64, nw = (wave >> 1) * 64;
  int l15 = lane & 15, l4 = lane >> 4;

  floatx4 acc[4][4];
#pragma unroll
  for (int mt = 0; mt < 4; ++mt)
#pragma unroll
    for (int nt = 0; nt < 4; ++nt) acc[mt][nt] = (floatx4){0.f, 0.f, 0.f, 0.f};

  const size_t bC = (size_t)b * NC;
  for (int k0 = 0; k0 < 512; k0 += 64) {
    // stage 128x64 A and B panels; pre-swizzled source slot, linear LDS dest
#pragma unroll
    for (int rep = 0; rep < 4; ++rep) {
      int chunk = rep * 256 + tid;       // 1024 chunks of 16B per matrix
      int r = chunk >> 3;                // row 0..127
      int s = chunk & 7;                 // 16B slot in row
      int ss = (s ^ (r & 7)) * 8;        // swizzled source k-offset (f16 units)
      __builtin_amdgcn_global_load_lds(AS1(adjH + (size_t)(i0 + r) * 512 + k0 + ss),
                                       AS3(&As[chunk * 8]), 16, 0, 0);
      __builtin_amdgcn_global_load_lds(AS1(xT + (bC + c0 + r) * 512 + k0 + ss),
                                       AS3(&Bs[chunk * 8]), 16, 0, 0);
    }
    __syncthreads();
#pragma unroll
    for (int ks = 0; ks < 2; ++ks) {
      half8 af[4], bfv[4];
#pragma unroll
      for (int mt = 0; mt < 4; ++mt) {
        int row = mw + mt * 16 + l15;
        int slot = (ks * 4 + l4) ^ (row & 7);
        af[mt] = *(const half8*)&As[row * 64 + slot * 8];
      }
#pragma unroll
      for (int nt = 0; nt < 4; ++nt) {
        int row = nw + nt * 16 + l15;
        int slot = (ks * 4 + l4) ^ (row & 7);
        bfv[nt] = *(const half8*)&Bs[row * 64 + slot * 8];
      }
#pragma unroll
      for (int mt = 0; mt < 4; ++mt)
#pragma unroll
        for (int nt = 0; nt < 4; ++nt)
          acc[mt][nt] = __builtin_amdgcn_mfma_f32_16x16x32_f16(af[mt], bfv[nt], acc[mt][nt], 0, 0, 0);
    }
    __syncthreads();
  }

  // Epilogue: two 64-row halves. h=0 -> waves 0,2 (mw=0); h=1 -> waves 1,3.
  const size_t bE = (size_t)b * N_;
  for (int h = 0; h < 2; ++h) {
    // stage E0 tile half: 64 rows x 128 c f16 = 16 KB, coalesced
#pragma unroll
    for (int it = 0; it < 4; ++it) {
      int chunk = it * 256 + tid;        // 1024 x 16B
      int row = chunk >> 4;
      int c8 = (chunk & 15) * 8;
      __builtin_amdgcn_global_load_lds(
          AS1(E0 + (bE + i0 + h * 64 + row) * NC + c0 + c8),
          AS3(&Es[chunk * 8]), 16, 0, 0);
    }
    if ((wave & 1) == h) {
#pragma unroll
      for (int mt = 0; mt < 4; ++mt)
#pragma unroll
        for (int nt = 0; nt < 4; ++nt)
#pragma unroll
          for (int r = 0; r < 4; ++r)
            accS[(mt * 16 + l4 * 4 + r) * 132 + nw + nt * 16 + l15] = acc[mt][nt][r];
    }
    __syncthreads();   // drains vmcnt: Es + accS both ready

    {
      int f = tid & 63;
      int rj = tid >> 6;
#pragma unroll
      for (int jj = 0; jj < 16; ++jj) {
        int row = rj + 4 * jj;
        int grow = i0 + h * 64 + row;
        float v0 = accS[row * 132 + f]      + (float)Es[row * 128 + f];
        float v1 = accS[row * 132 + 64 + f] + (float)Es[row * 128 + 64 + f];
        size_t o = (((size_t)(b * N_ + grow)) * T_ + t0) * FA_ + f;
        out[o] = fmaxf(v0, 0.f);
        out[o + FA_] = fmaxf(v1, 0.f);
      }
    }
    __syncthreads();   // before next h overwrites accS/Es
  }
}

extern "C" void kernel_launch(void* const* d_in, const int* in_sizes, int n_in,
                              void* d_out, int out_size, void* d_ws, size_t ws_size,
                              hipStream_t stream) {
  const float* x     = (const float*)d_in[0];
  const float* adj   = (const float*)d_in[1];
  const float* alpha = (const float*)d_in[2];
  const float* w     = (const float*)d_in[3];
  const float* d     = (const float*)d_in[4];
  const float* w2    = (const float*)d_in[5];
  const float* d2    = (const float*)d_in[6];
  float* out = (float*)d_out;
  float* ws  = (float*)d_ws;

  hipLaunchKernelGGL(params_kernel, dim3(1), dim3(256), 0, stream, w, d, w2, d2, ws);
  hipLaunchKernelGGL(convert_adj_kernel, dim3(256), dim3(256), 0, stream, adj, alpha, ws);
  hipLaunchKernelGGL(transpose_x_kernel, dim3(24, 8, B_), dim3(256), 0, stream, x, ws);
  hipLaunchKernelGGL(e_kernel, dim3(B_ * (N_ / 4)), dim3(256), 0, stream, x, ws, out);
  hipLaunchKernelGGL(gemm_kernel, dim3(12, 4, B_), dim3(256), 0, stream, ws, out);
}